// Round 8
// baseline (93.002 us; speedup 1.0000x reference)
//
#include <hip/hip_runtime.h>
#include <stdint.h>

#define TSEQ 4096
#define DMODEL 1024
#define N3 3072
#define NHEADS 16
#define HDIM 64
#define WINDOW 256

typedef __attribute__((ext_vector_type(8))) short short8;
typedef __attribute__((ext_vector_type(4))) float f32x4;

__device__ __forceinline__ unsigned short f2bf(float f) {
  unsigned u = __builtin_bit_cast(unsigned, f);
  return (unsigned short)((u + 0x7fffu + ((u >> 16) & 1u)) >> 16);
}

__device__ __forceinline__ unsigned cvtpk(float lo, float hi) {
  unsigned r;
  asm("v_cvt_pk_bf16_f32 %0, %1, %2" : "=v"(r) : "v"(lo), "v"(hi));
  return r;
}

__device__ __forceinline__ f32x4 mfma16(short8 a, short8 b, f32x4 c) {
  return __builtin_amdgcn_mfma_f32_16x16x32_bf16(a, b, c, 0, 0, 0);
}

// async global->LDS, 16B per lane; lds dest must be wave-uniform base (HW adds lane*16)
__device__ __forceinline__ void g2lds16(const void* g, void* l) {
  __builtin_amdgcn_global_load_lds(
      (const __attribute__((address_space(1))) void*)(uintptr_t)g,
      (__attribute__((address_space(3))) void*)(uintptr_t)l,
      16, 0, 0);
}

// ---------------- fused prep: x cvt + both weight transposes ----------------
// blocks [0,4096): x f32 -> bf16 (16B/thread). blocks [4096,8192): 32x32 transpose tiles.

__global__ __launch_bounds__(256) void prep(const float* __restrict__ x,
                                            const float* __restrict__ Wqkv,
                                            const float* __restrict__ Wproj,
                                            unsigned short* __restrict__ xb,
                                            unsigned short* __restrict__ oQkvT,
                                            unsigned short* __restrict__ oProjT) {
  __shared__ float tile[32][33];
  int b = blockIdx.x;
  int tid = threadIdx.x;
  if (b < 4096) {
    int i = (b * 256 + tid) * 4;
    float4 v = *(const float4*)(x + i);
    unsigned lo = cvtpk(v.x, v.y), hi = cvtpk(v.z, v.w);
    unsigned long long packed = (unsigned long long)lo | ((unsigned long long)hi << 32);
    *(unsigned long long*)(xb + i) = packed;
    return;
  }
  b -= 4096;
  int bx = b & 127, by = b >> 7;
  const float* in;
  unsigned short* out;
  int C;
  if (bx < 96) {
    in = Wqkv; out = oQkvT; C = N3;
  } else {
    bx -= 96; in = Wproj; out = oProjT; C = DMODEL;
  }
  const int R = DMODEL;
  int c0 = bx * 32;
  int r0 = by * 32;
  int tx = tid & 31, ty = tid >> 5;
#pragma unroll
  for (int i = 0; i < 32; i += 8)
    tile[ty + i][tx] = in[(size_t)(r0 + ty + i) * C + c0 + tx];
  __syncthreads();
#pragma unroll
  for (int i = 0; i < 32; i += 8)
    out[(size_t)(c0 + ty + i) * R + r0 + tx] = f2bf(tile[tx][ty + i]);
}

// ---------------- GEMM: C[M][N] = A[M][K=1024] * BT[N][K]^T + bias ----------------
// Tile (MI*32) x (NI*32). EPI=0: scatter to Q (pre-scaled 1/8), K, VT. EPI=1: f32 out.
// ROUND-8: occupancy is the lever (r5-r7: schedule changes flat; grid 3 blocks/CU
// capped occupancy at 37%). QKV now 128x64 -> 1536 blocks = 6/CU (24 waves, 75% cap);
// proj 64x64 -> 1024 blocks = 4/CU. 2-buffer ping-pong, counted vmcnt (stage s+1 in
// flight across compute s). LDS 24KB/16KB -> occupancy not LDS-limited.
// Staging source pre-swizzled by ((row>>1)&3)<<4, same XOR on LDS read (rule 21):
// bank conflicts measured 0 since round 5.

template <int EPI, int MI, int NI>
__global__ __launch_bounds__(256)
void gemm_bf16(const unsigned short* __restrict__ A,
               const unsigned short* __restrict__ BT,
               const float* __restrict__ bias,
               unsigned short* __restrict__ oQ,
               unsigned short* __restrict__ oK,
               unsigned short* __restrict__ oVT,
               float* __restrict__ oF) {
  constexpr int BM = MI * 32, BN = NI * 32;
  constexpr int LPS = MI / 2 + NI / 2;  // g2lds per wave per stage
  __shared__ unsigned short Asm[2][BM * 32];
  __shared__ unsigned short Bsm[2][BN * 32];
  const int K = 1024;
  int m0 = blockIdx.x * BM;   // no XCD swizzle: default bx%8 partitioning already
  int n0 = blockIdx.y * BN;   // splits A-panels across XCDs (round-2 post-mortem)
  int tid = threadIdx.x;
  int w = tid >> 6, lane = tid & 63;
  int l15 = lane & 15, l4 = lane >> 4;
  int wm = (w >> 1) * (MI * 16), wn = (w & 1) * (NI * 16);

  f32x4 acc[MI][NI];
#pragma unroll
  for (int i = 0; i < MI; i++)
#pragma unroll
    for (int j = 0; j < NI; j++) acc[i][j] = (f32x4){0.f, 0.f, 0.f, 0.f};

  // staging: wave w covers A rows w*(BM/4)..+BM/4-1, B rows w*(BN/4).. (16-row/1KB chunks)
  int lr = lane >> 2;
  int slot = ((lane & 3) * 16) ^ (((lr >> 1) & 3) << 4);
  const char* aG = (const char*)(A + (size_t)(m0 + w * (BM / 4) + lr) * K) + slot;
  const char* bG = (const char*)(BT + (size_t)(n0 + w * (BN / 4) + lr) * K) + slot;
  const size_t rowSkip = (size_t)16 * K * 2;  // +16 rows, bytes

  auto stage = [&](int s, int b) {   // step s covers k = s*32..s*32+31
    int koff = s * 64;               // bytes within row
#pragma unroll
    for (int j = 0; j < MI / 2; j++)
      g2lds16(aG + j * rowSkip + koff, &Asm[b][(w * (MI / 2) + j) * 512]);
#pragma unroll
    for (int j = 0; j < NI / 2; j++)
      g2lds16(bG + j * rowSkip + koff, &Bsm[b][(w * (NI / 2) + j) * 512]);
  };

  int sX = ((l15 >> 1) & 3) << 4;    // read-side swizzle (row bits 1-2 == l15 bits 1-2)

  auto compute = [&](int b) {
    short8 af[MI], bfr[NI];
#pragma unroll
    for (int mi = 0; mi < MI; mi++) {
      int rA = wm + mi * 16 + l15;
      af[mi] = *(const short8*)((const char*)Asm[b] + rA * 64 + ((l4 * 16) ^ sX));
    }
#pragma unroll
    for (int ni = 0; ni < NI; ni++) {
      int rB = wn + ni * 16 + l15;
      bfr[ni] = *(const short8*)((const char*)Bsm[b] + rB * 64 + ((l4 * 16) ^ sX));
    }
#pragma unroll
    for (int mi = 0; mi < MI; mi++)
#pragma unroll
      for (int ni = 0; ni < NI; ni++)
        acc[mi][ni] = mfma16(af[mi], bfr[ni], acc[mi][ni]);
  };

  const int NS = K / 32;  // 32 steps
  stage(0, 0);
#pragma unroll 1
  for (int s = 0; s < NS; s++) {
    if (s + 1 < NS) {
      stage(s + 1, (s + 1) & 1);
      // stage(s) landed; stage(s+1)'s LPS loads stay in flight
      if constexpr (LPS == 3) asm volatile("s_waitcnt vmcnt(3)" ::: "memory");
      else if constexpr (LPS == 2) asm volatile("s_waitcnt vmcnt(2)" ::: "memory");
      else asm volatile("s_waitcnt vmcnt(4)" ::: "memory");
    } else {
      asm volatile("s_waitcnt vmcnt(0)" ::: "memory");
    }
    __builtin_amdgcn_s_barrier();
    __builtin_amdgcn_sched_barrier(0);
    compute(s & 1);
    __builtin_amdgcn_sched_barrier(0);
    __builtin_amdgcn_s_barrier();   // all waves done reading buf before it's restaged
  }

#pragma unroll
  for (int ni = 0; ni < NI; ni++) {
    int nn = n0 + wn + ni * 16 + l15;
    float bv = bias[nn];
    int c = nn & 1023;
    int hh = c >> 6, dd = c & 63;
#pragma unroll
    for (int mi = 0; mi < MI; mi++) {
      int mm = m0 + wm + mi * 16 + l4 * 4;
      float v0 = acc[mi][ni][0] + bv;
      float v1 = acc[mi][ni][1] + bv;
      float v2 = acc[mi][ni][2] + bv;
      float v3 = acc[mi][ni][3] + bv;
      if (EPI == 1) {
        oF[(size_t)(mm + 0) * 1024 + nn] = v0;
        oF[(size_t)(mm + 1) * 1024 + nn] = v1;
        oF[(size_t)(mm + 2) * 1024 + nn] = v2;
        oF[(size_t)(mm + 3) * 1024 + nn] = v3;
      } else if (nn < 1024) {
        oQ[((size_t)hh * TSEQ + mm + 0) * 64 + dd] = f2bf(v0 * 0.125f);
        oQ[((size_t)hh * TSEQ + mm + 1) * 64 + dd] = f2bf(v1 * 0.125f);
        oQ[((size_t)hh * TSEQ + mm + 2) * 64 + dd] = f2bf(v2 * 0.125f);
        oQ[((size_t)hh * TSEQ + mm + 3) * 64 + dd] = f2bf(v3 * 0.125f);
      } else if (nn < 2048) {
        oK[((size_t)hh * TSEQ + mm + 0) * 64 + dd] = f2bf(v0);
        oK[((size_t)hh * TSEQ + mm + 1) * 64 + dd] = f2bf(v1);
        oK[((size_t)hh * TSEQ + mm + 2) * 64 + dd] = f2bf(v2);
        oK[((size_t)hh * TSEQ + mm + 3) * 64 + dd] = f2bf(v3);
      } else {
        unsigned lo = cvtpk(v0, v1), hi = cvtpk(v2, v3);
        unsigned long long pv = (unsigned long long)lo | ((unsigned long long)hi << 32);
        *(unsigned long long*)(oVT + ((size_t)hh * 64 + dd) * TSEQ + mm) = pv;
      }
    }
  }
}

// ---------------- sliding-window attention (LDS-staged, double-buffered) ----------------
// grid 1024 (XCD-swizzled -> 2 heads/XCD), 4 waves; wave w owns q rows qb*64+w*16..+15
// Per tile: 4 waves cooperatively stage K(8KB)+V(8KB) via global_load_lds, double-buffered
// with counted vmcnt(4). Source pre-swizzled + swizzled LDS reads (rule 21).
// S^T = mfma(K,Q); PV = mfma(V,P^T): softmax + rescale + 1/l all lane-local (q=lane&15).

__global__ __launch_bounds__(256)
void attn_swa(const unsigned short* __restrict__ Qa,
              const unsigned short* __restrict__ Ka,
              const unsigned short* __restrict__ Vt,
              unsigned short* __restrict__ Y) {
  __shared__ __align__(16) char KV[2][16384];   // [buf][ K 8KB | V 8KB ]
  __shared__ __align__(16) unsigned char Pl[4][2048];
  int flat = blockIdx.x;
  int swz = (flat & 7) * 128 + (flat >> 3);   // bijective; 2 heads/XCD
  int h = swz >> 6, qb = swz & 63;
  int w = threadIdx.x >> 6, lane = threadIdx.x & 63;
  int l15 = lane & 15, l4 = lane >> 4;
  int qrow0 = qb * 64 + w * 16;
  int q = qrow0 + l15;

  // Q fragments (pre-scaled by 1/8 in the QKV epilogue)
  const unsigned short* qp = Qa + ((size_t)h * TSEQ + q) * 64 + l4 * 8;
  short8 qf0 = *(const short8*)qp;
  short8 qf1 = *(const short8*)(qp + 32);

  const char* kgb = (const char*)(Ka + (size_t)h * TSEQ * 64);
  const char* vgb = (const char*)(Vt + (size_t)h * 64 * TSEQ);

  // stage tile kt into buffer b: waves 0,1 -> K rows w*32..+31; waves 2,3 -> V d-rows
  auto stage = [&](int kt, int b) {
    int kbase = kt * 64;
    int sub = lane >> 3, slot = (lane & 7) * 16;
    if (w < 2) {
      int R0 = w * 32;
      const char* src = kgb + (size_t)kbase * 128;
#pragma unroll
      for (int j = 0; j < 4; j++) {
        int r = R0 + j * 8 + sub;
        g2lds16(src + r * 128 + (slot ^ ((r & 7) << 4)), &KV[b][R0 * 128 + j * 1024]);
      }
    } else {
      int D0 = (w - 2) * 32;
      const char* src = vgb + (size_t)kbase * 2;
#pragma unroll
      for (int j = 0; j < 4; j++) {
        int d = D0 + j * 8 + sub;
        g2lds16(src + (size_t)d * 8192 + (slot ^ ((d & 7) << 4)),
                &KV[b][8192 + D0 * 128 + j * 1024]);
      }
    }
  };

  float m = -1e30f, lsum = 0.f;
  f32x4 o[4];
#pragma unroll
  for (int ni = 0; ni < 4; ni++) o[ni] = (f32x4){0.f, 0.f, 0.f, 0.f};

  unsigned char* pw = Pl[w];
  int xw = (l15 & 7) << 4;  // row&7 == l15&7 for rows ni*16+l15

  // MODE: 0 = interior, 1 = window edge (q-key<256), 2 = causal diag (key<=q)
  auto compute = [&](int kt, int b, int MODE) {
    int kbase = kt * 64;
    const char* kb = KV[b];
    const char* vb = KV[b] + 8192;
    f32x4 s[4];
#pragma unroll
    for (int ni = 0; ni < 4; ni++) {
      int rb = (ni * 16 + l15) * 128;
      short8 k0 = *(const short8*)(kb + rb + ((l4 * 16) ^ xw));
      short8 k1 = *(const short8*)(kb + rb + ((64 + l4 * 16) ^ xw));
      f32x4 z = (f32x4){0.f, 0.f, 0.f, 0.f};
      z = mfma16(k0, qf0, z);
      s[ni] = mfma16(k1, qf1, z);
    }
    if (MODE != 0) {
#pragma unroll
      for (int ni = 0; ni < 4; ni++)
#pragma unroll
        for (int r = 0; r < 4; r++) {
          int key = kbase + ni * 16 + l4 * 4 + r;
          bool ok = (MODE == 2) ? (key <= q) : (q - key < WINDOW);
          s[ni][r] = ok ? s[ni][r] : -1e30f;
        }
    }
    float pm0 = fmaxf(fmaxf(s[0][0], s[0][1]), fmaxf(s[0][2], s[0][3]));
    float pm1 = fmaxf(fmaxf(s[1][0], s[1][1]), fmaxf(s[1][2], s[1][3]));
    float pm2 = fmaxf(fmaxf(s[2][0], s[2][1]), fmaxf(s[2][2], s[2][3]));
    float pm3 = fmaxf(fmaxf(s[3][0], s[3][1]), fmaxf(s[3][2], s[3][3]));
    float pm = fmaxf(fmaxf(pm0, pm1), fmaxf(pm2, pm3));
    pm = fmaxf(pm, __shfl_xor(pm, 16, 64));
    pm = fmaxf(pm, __shfl_xor(pm, 32, 64));
    float mn = fmaxf(m, pm);
    float alpha = __expf(m - mn);
    m = mn;
    float rs = 0.f;
#pragma unroll
    for (int ni = 0; ni < 4; ni++)
#pragma unroll
      for (int r = 0; r < 4; r++) {
        float p = __expf(s[ni][r] - mn);
        s[ni][r] = p;
        rs += p;
      }
    rs += __shfl_xor(rs, 16, 64);
    rs += __shfl_xor(rs, 32, 64);
    lsum = lsum * alpha + rs;
    // P -> per-wave LDS (cvt_pk packed, row-XOR swizzled both sides)
#pragma unroll
    for (int ni = 0; ni < 4; ni++) {
      unsigned lo = cvtpk(s[ni][0], s[ni][1]);
      unsigned hi = cvtpk(s[ni][2], s[ni][3]);
      unsigned long long pv = (unsigned long long)lo | ((unsigned long long)hi << 32);
      *(unsigned long long*)(pw + l15 * 128 + ((ni * 32 + l4 * 8) ^ xw)) = pv;
    }
    short8 pa0 = *(const short8*)(pw + l15 * 128 + ((l4 * 16) ^ xw));
    short8 pa1 = *(const short8*)(pw + l15 * 128 + ((64 + l4 * 16) ^ xw));
#pragma unroll
    for (int ni = 0; ni < 4; ni++)
#pragma unroll
      for (int r = 0; r < 4; r++) o[ni][r] *= alpha;
#pragma unroll
    for (int ni = 0; ni < 4; ni++) {
      int rb = (ni * 16 + l15) * 128;
      short8 v0 = *(const short8*)(vb + rb + ((l4 * 16) ^ xw));
      short8 v1 = *(const short8*)(vb + rb + ((64 + l4 * 16) ^ xw));
      o[ni] = mfma16(v0, pa0, o[ni]);
      o[ni] = mfma16(v1, pa1, o[ni]);
    }
  };

  int kt0 = qb >= 4 ? qb - 4 : 0;
  int NT = qb - kt0 + 1;
  stage(kt0, 0);
  for (int t = 0; t < NT; t++) {
    int kt = kt0 + t;
    if (t + 1 < NT) {
      stage(kt + 1, (t + 1) & 1);
      asm volatile("s_waitcnt vmcnt(4)" ::: "memory");
    } else {
      asm volatile("s_waitcnt vmcnt(0)" ::: "memory");
    }
    __builtin_amdgcn_s_barrier();
    __builtin_amdgcn_sched_barrier(0);
    int MODE = (t == NT - 1) ? 2 : ((qb >= 4 && t == 0) ? 1 : 0);
    compute(kt, t & 1, MODE);
    __builtin_amdgcn_sched_barrier(0);
    __builtin_amdgcn_s_barrier();
  }

  float inv = 1.f / lsum;
#pragma unroll
  for (int ni = 0; ni < 4; ni++) {
    unsigned lo = cvtpk(o[ni][0] * inv, o[ni][1] * inv);
    unsigned hi = cvtpk(o[ni][2] * inv, o[ni][3] * inv);
    unsigned long long yv = (unsigned long long)lo | ((unsigned long long)hi << 32);
    *(unsigned long long*)(Y + (size_t)q * DMODEL + h * 64 + ni * 16 + l4 * 4) = yv;
  }
}

// ---------------- launch ----------------

extern "C" void kernel_launch(void* const* d_in, const int* in_sizes, int n_in,
                              void* d_out, int out_size, void* d_ws, size_t ws_size,
                              hipStream_t stream) {
  const float* x = (const float*)d_in[0];
  const float* Wqkv = (const float*)d_in[1];
  const float* bqkv = (const float*)d_in[2];
  const float* Wproj = (const float*)d_in[3];
  const float* bproj = (const float*)d_in[4];
  float* out = (float*)d_out;

  unsigned short* ws = (unsigned short*)d_ws;
  unsigned short* xb = ws;                                        // [4096][1024]
  unsigned short* wqkvT = xb + (size_t)TSEQ * DMODEL;             // [3072][1024]
  unsigned short* wprojT = wqkvT + (size_t)N3 * DMODEL;           // [1024][1024]
  unsigned short* qarr = wprojT + (size_t)DMODEL * DMODEL;        // [16][4096][64] (pre-scaled 1/8)
  unsigned short* karr = qarr + (size_t)NHEADS * TSEQ * HDIM;     // [16][4096][64]
  unsigned short* vtarr = karr + (size_t)NHEADS * TSEQ * HDIM;    // [16][64][4096]
  unsigned short* yarr = vtarr + (size_t)NHEADS * TSEQ * HDIM;    // [4096][1024]

  prep<<<8192, 256, 0, stream>>>(x, Wqkv, Wproj, xb, wqkvT, wprojT);
  gemm_bf16<0, 4, 2><<<dim3(TSEQ / 128, N3 / 64), 256, 0, stream>>>(xb, wqkvT, bqkv, qarr, karr, vtarr, nullptr);
  attn_swa<<<1024, 256, 0, stream>>>(qarr, karr, vtarr, yarr);
  gemm_bf16<1, 2, 2><<<dim3(TSEQ / 64, DMODEL / 64), 256, 0, stream>>>(yarr, wprojT, bproj, nullptr, nullptr, nullptr, out);
}

// Round 9
// 87.830 us; speedup vs baseline: 1.0589x; 1.0589x over previous
//
#include <hip/hip_runtime.h>
#include <stdint.h>

#define TSEQ 4096
#define DMODEL 1024
#define N3 3072
#define NHEADS 16
#define HDIM 64
#define WINDOW 256

typedef __attribute__((ext_vector_type(8))) short short8;
typedef __attribute__((ext_vector_type(4))) float f32x4;

__device__ __forceinline__ unsigned short f2bf(float f) {
  unsigned u = __builtin_bit_cast(unsigned, f);
  return (unsigned short)((u + 0x7fffu + ((u >> 16) & 1u)) >> 16);
}

__device__ __forceinline__ unsigned cvtpk(float lo, float hi) {
  unsigned r;
  asm("v_cvt_pk_bf16_f32 %0, %1, %2" : "=v"(r) : "v"(lo), "v"(hi));
  return r;
}

__device__ __forceinline__ f32x4 mfma16(short8 a, short8 b, f32x4 c) {
  return __builtin_amdgcn_mfma_f32_16x16x32_bf16(a, b, c, 0, 0, 0);
}

// async global->LDS, 16B per lane; lds dest must be wave-uniform base (HW adds lane*16)
__device__ __forceinline__ void g2lds16(const void* g, void* l) {
  __builtin_amdgcn_global_load_lds(
      (const __attribute__((address_space(1))) void*)(uintptr_t)g,
      (__attribute__((address_space(3))) void*)(uintptr_t)l,
      16, 0, 0);
}

// ---------------- prep: weight transposes only (x consumed as f32 by GEMM) ----------------

__global__ __launch_bounds__(256) void prep(const float* __restrict__ Wqkv,
                                            const float* __restrict__ Wproj,
                                            unsigned short* __restrict__ oQkvT,
                                            unsigned short* __restrict__ oProjT) {
  __shared__ float tile[32][33];
  int bx = blockIdx.x;
  const float* in;
  unsigned short* out;
  int C;
  if (bx < 96) {
    in = Wqkv; out = oQkvT; C = N3;
  } else {
    bx -= 96; in = Wproj; out = oProjT; C = DMODEL;
  }
  const int R = DMODEL;
  int c0 = bx * 32;
  int r0 = blockIdx.y * 32;
  int tid = threadIdx.x;
  int tx = tid & 31, ty = tid >> 5;
#pragma unroll
  for (int i = 0; i < 32; i += 8)
    tile[ty + i][tx] = in[(size_t)(r0 + ty + i) * C + c0 + tx];
  __syncthreads();
#pragma unroll
  for (int i = 0; i < 32; i += 8)
    out[(size_t)(c0 + ty + i) * R + r0 + tx] = f2bf(tile[tx][ty + i]);
}

// ---------------- GEMM: C[M][N] = A[M][K=1024] * BT[N][K]^T + bias ----------------
// Tile (MI*32)x(NI*32). AF32: A read as f32 (row stride 4096B), staged f32 to LDS,
// converted to bf16 in-register via v_cvt_pk after ds_read (kills the x-cvt prep pass).
// EPI=0: scatter to Q (pre-scaled 1/8), K, VT (bf16). EPI=1: f32 out.
// r5-best structure: 2-buffer ping-pong, counted vmcnt (stage s+1 in flight across
// compute s), 2 barriers/step. Five schedule variants (r5-r8) all ~equal: this family
// is at its ceiling; this round removes pipeline work instead.
// Staging source pre-swizzled, same XOR on LDS read (rule 21); bank conflicts 0 (r5).
// A-f32 swizzle: slot ^= (row&7), even 8-lane/slot spread over 8x16B slots per 128B row.

template <int EPI, bool AF32, int MI, int NI>
__global__ __launch_bounds__(256)
void gemm_bf16(const void* __restrict__ Ap,
               const unsigned short* __restrict__ BT,
               const float* __restrict__ bias,
               unsigned short* __restrict__ oQ,
               unsigned short* __restrict__ oK,
               unsigned short* __restrict__ oVT,
               float* __restrict__ oF) {
  constexpr int BM = MI * 32, BN = NI * 32;
  constexpr int ABY = AF32 ? BM * 32 * 4 : BM * 32 * 2;  // bytes per A buffer
  constexpr int BBY = BN * 32 * 2;
  constexpr int LPS = (AF32 ? MI : MI / 2) + NI / 2;  // g2lds per wave per stage
  __shared__ __align__(16) char Asm[2][ABY];
  __shared__ __align__(16) char Bsm[2][BBY];
  const int K = 1024;
  int m0 = blockIdx.x * BM;   // no XCD swizzle: default bx%8 partitioning already
  int n0 = blockIdx.y * BN;   // splits A-panels across XCDs (round-2 post-mortem)
  int tid = threadIdx.x;
  int w = tid >> 6, lane = tid & 63;
  int l15 = lane & 15, l4 = lane >> 4;
  int wm = (w >> 1) * (MI * 16), wn = (w & 1) * (NI * 16);

  f32x4 acc[MI][NI];
#pragma unroll
  for (int i = 0; i < MI; i++)
#pragma unroll
    for (int j = 0; j < NI; j++) acc[i][j] = (f32x4){0.f, 0.f, 0.f, 0.f};

  // A staging: wave w covers rows w*(BM/4)..+BM/4-1
  const char* aG;
  if constexpr (AF32) {
    int sub8 = lane >> 3;                       // row within 8-row chunk
    int slotA = ((lane & 7) ^ sub8) * 16;       // pre-swizzled 16B slot in 128B k-slice
    aG = (const char*)Ap + (size_t)(m0 + w * (MI * 8) + sub8) * 4096 + slotA;
  } else {
    int lr = lane >> 2;
    int slotB = ((lane & 3) * 16) ^ (((lr >> 1) & 3) << 4);
    aG = (const char*)Ap + (size_t)(m0 + w * (MI * 8) + lr) * 2048 + slotB;
  }
  const char* bG;
  {
    int lr = lane >> 2;
    int slotB = ((lane & 3) * 16) ^ (((lr >> 1) & 3) << 4);
    bG = (const char*)BT + (size_t)(n0 + w * (NI * 8) + lr) * 2048 + slotB;
  }

  auto stage = [&](int s, int b) {   // step s covers k = s*32..s*32+31
    if constexpr (AF32) {
      int koff = s * 128;            // bytes within f32 row
#pragma unroll
      for (int c = 0; c < MI; c++)   // MI chunks of 8 rows (1KB each)
        g2lds16(aG + (size_t)c * 8 * 4096 + koff, &Asm[b][(w * MI + c) * 1024]);
    } else {
      int koff = s * 64;
#pragma unroll
      for (int c = 0; c < MI / 2; c++)
        g2lds16(aG + (size_t)c * 16 * 2048 + koff, &Asm[b][(w * (MI / 2) + c) * 1024]);
    }
    int koff = s * 64;
#pragma unroll
    for (int j = 0; j < NI / 2; j++)
      g2lds16(bG + (size_t)j * 16 * 2048 + koff, &Bsm[b][(w * (NI / 2) + j) * 1024]);
  };

  int sX = ((l15 >> 1) & 3) << 4;    // bf16 read-side swizzle
  int swA = (l15 & 7) << 4;          // f32-A read-side swizzle

  auto compute = [&](int b) {
    short8 af[MI], bfr[NI];
#pragma unroll
    for (int mi = 0; mi < MI; mi++) {
      int rA = wm + mi * 16 + l15;
      if constexpr (AF32) {
        const char* base = Asm[b] + rA * 128;
        f32x4 lo = *(const f32x4*)(base + ((l4 * 32) ^ swA));
        f32x4 hi = *(const f32x4*)(base + ((l4 * 32 + 16) ^ swA));
        union { short8 s; unsigned u[4]; } t;
        t.u[0] = cvtpk(lo[0], lo[1]);
        t.u[1] = cvtpk(lo[2], lo[3]);
        t.u[2] = cvtpk(hi[0], hi[1]);
        t.u[3] = cvtpk(hi[2], hi[3]);
        af[mi] = t.s;
      } else {
        af[mi] = *(const short8*)(Asm[b] + rA * 64 + ((l4 * 16) ^ sX));
      }
    }
#pragma unroll
    for (int ni = 0; ni < NI; ni++) {
      int rB = wn + ni * 16 + l15;
      bfr[ni] = *(const short8*)(Bsm[b] + rB * 64 + ((l4 * 16) ^ sX));
    }
    __builtin_amdgcn_s_setprio(1);
#pragma unroll
    for (int mi = 0; mi < MI; mi++)
#pragma unroll
      for (int ni = 0; ni < NI; ni++)
        acc[mi][ni] = mfma16(af[mi], bfr[ni], acc[mi][ni]);
    __builtin_amdgcn_s_setprio(0);
  };

  const int NS = K / 32;  // 32 steps
  stage(0, 0);
#pragma unroll 1
  for (int s = 0; s < NS; s++) {
    if (s + 1 < NS) {
      stage(s + 1, (s + 1) & 1);
      // stage(s) landed; stage(s+1)'s LPS loads stay in flight
      if constexpr (LPS == 6) asm volatile("s_waitcnt vmcnt(6)" ::: "memory");
      else if constexpr (LPS == 4) asm volatile("s_waitcnt vmcnt(4)" ::: "memory");
      else asm volatile("s_waitcnt vmcnt(2)" ::: "memory");
    } else {
      asm volatile("s_waitcnt vmcnt(0)" ::: "memory");
    }
    __builtin_amdgcn_s_barrier();
    __builtin_amdgcn_sched_barrier(0);
    compute(s & 1);
    __builtin_amdgcn_sched_barrier(0);
    __builtin_amdgcn_s_barrier();   // all waves done reading buf before it's restaged
  }

#pragma unroll
  for (int ni = 0; ni < NI; ni++) {
    int nn = n0 + wn + ni * 16 + l15;
    float bv = bias[nn];
    int c = nn & 1023;
    int hh = c >> 6, dd = c & 63;
#pragma unroll
    for (int mi = 0; mi < MI; mi++) {
      int mm = m0 + wm + mi * 16 + l4 * 4;
      float v0 = acc[mi][ni][0] + bv;
      float v1 = acc[mi][ni][1] + bv;
      float v2 = acc[mi][ni][2] + bv;
      float v3 = acc[mi][ni][3] + bv;
      if (EPI == 1) {
        oF[(size_t)(mm + 0) * 1024 + nn] = v0;
        oF[(size_t)(mm + 1) * 1024 + nn] = v1;
        oF[(size_t)(mm + 2) * 1024 + nn] = v2;
        oF[(size_t)(mm + 3) * 1024 + nn] = v3;
      } else if (nn < 1024) {
        oQ[((size_t)hh * TSEQ + mm + 0) * 64 + dd] = f2bf(v0 * 0.125f);
        oQ[((size_t)hh * TSEQ + mm + 1) * 64 + dd] = f2bf(v1 * 0.125f);
        oQ[((size_t)hh * TSEQ + mm + 2) * 64 + dd] = f2bf(v2 * 0.125f);
        oQ[((size_t)hh * TSEQ + mm + 3) * 64 + dd] = f2bf(v3 * 0.125f);
      } else if (nn < 2048) {
        oK[((size_t)hh * TSEQ + mm + 0) * 64 + dd] = f2bf(v0);
        oK[((size_t)hh * TSEQ + mm + 1) * 64 + dd] = f2bf(v1);
        oK[((size_t)hh * TSEQ + mm + 2) * 64 + dd] = f2bf(v2);
        oK[((size_t)hh * TSEQ + mm + 3) * 64 + dd] = f2bf(v3);
      } else {
        unsigned lo = cvtpk(v0, v1), hi = cvtpk(v2, v3);
        unsigned long long pv = (unsigned long long)lo | ((unsigned long long)hi << 32);
        *(unsigned long long*)(oVT + ((size_t)hh * 64 + dd) * TSEQ + mm) = pv;
      }
    }
  }
}

// ---------------- sliding-window attention (LDS-staged, double-buffered) ----------------
// grid 1024 (XCD-swizzled -> 2 heads/XCD), 4 waves; wave w owns q rows qb*64+w*16..+15
// Per tile: 4 waves cooperatively stage K(8KB)+V(8KB) via global_load_lds, double-buffered
// with counted vmcnt(4). Source pre-swizzled + swizzled LDS reads (rule 21).
// S^T = mfma(K,Q); PV = mfma(V,P^T): softmax + rescale + 1/l all lane-local (q=lane&15).
// r9: setprio around MFMA clusters (T5, m191 +4-7%); defer-max branch (T13, exact:
// alpha==1 when __all(pm<=m), skip the 17-op rescale).

__global__ __launch_bounds__(256)
void attn_swa(const unsigned short* __restrict__ Qa,
              const unsigned short* __restrict__ Ka,
              const unsigned short* __restrict__ Vt,
              unsigned short* __restrict__ Y) {
  __shared__ __align__(16) char KV[2][16384];   // [buf][ K 8KB | V 8KB ]
  __shared__ __align__(16) unsigned char Pl[4][2048];
  int flat = blockIdx.x;
  int swz = (flat & 7) * 128 + (flat >> 3);   // bijective; 2 heads/XCD
  int h = swz >> 6, qb = swz & 63;
  int w = threadIdx.x >> 6, lane = threadIdx.x & 63;
  int l15 = lane & 15, l4 = lane >> 4;
  int qrow0 = qb * 64 + w * 16;
  int q = qrow0 + l15;

  // Q fragments (pre-scaled by 1/8 in the QKV epilogue)
  const unsigned short* qp = Qa + ((size_t)h * TSEQ + q) * 64 + l4 * 8;
  short8 qf0 = *(const short8*)qp;
  short8 qf1 = *(const short8*)(qp + 32);

  const char* kgb = (const char*)(Ka + (size_t)h * TSEQ * 64);
  const char* vgb = (const char*)(Vt + (size_t)h * 64 * TSEQ);

  // stage tile kt into buffer b: waves 0,1 -> K rows w*32..+31; waves 2,3 -> V d-rows
  auto stage = [&](int kt, int b) {
    int kbase = kt * 64;
    int sub = lane >> 3, slot = (lane & 7) * 16;
    if (w < 2) {
      int R0 = w * 32;
      const char* src = kgb + (size_t)kbase * 128;
#pragma unroll
      for (int j = 0; j < 4; j++) {
        int r = R0 + j * 8 + sub;
        g2lds16(src + r * 128 + (slot ^ ((r & 7) << 4)), &KV[b][R0 * 128 + j * 1024]);
      }
    } else {
      int D0 = (w - 2) * 32;
      const char* src = vgb + (size_t)kbase * 2;
#pragma unroll
      for (int j = 0; j < 4; j++) {
        int d = D0 + j * 8 + sub;
        g2lds16(src + (size_t)d * 8192 + (slot ^ ((d & 7) << 4)),
                &KV[b][8192 + D0 * 128 + j * 1024]);
      }
    }
  };

  float m = -1e30f, lsum = 0.f;
  f32x4 o[4];
#pragma unroll
  for (int ni = 0; ni < 4; ni++) o[ni] = (f32x4){0.f, 0.f, 0.f, 0.f};

  unsigned char* pw = Pl[w];
  int xw = (l15 & 7) << 4;  // row&7 == l15&7 for rows ni*16+l15

  // MODE: 0 = interior, 1 = window edge (q-key<256), 2 = causal diag (key<=q)
  auto compute = [&](int kt, int b, int MODE) {
    int kbase = kt * 64;
    const char* kb = KV[b];
    const char* vb = KV[b] + 8192;
    f32x4 s[4];
    __builtin_amdgcn_s_setprio(1);
#pragma unroll
    for (int ni = 0; ni < 4; ni++) {
      int rb = (ni * 16 + l15) * 128;
      short8 k0 = *(const short8*)(kb + rb + ((l4 * 16) ^ xw));
      short8 k1 = *(const short8*)(kb + rb + ((64 + l4 * 16) ^ xw));
      f32x4 z = (f32x4){0.f, 0.f, 0.f, 0.f};
      z = mfma16(k0, qf0, z);
      s[ni] = mfma16(k1, qf1, z);
    }
    __builtin_amdgcn_s_setprio(0);
    if (MODE != 0) {
#pragma unroll
      for (int ni = 0; ni < 4; ni++)
#pragma unroll
        for (int r = 0; r < 4; r++) {
          int key = kbase + ni * 16 + l4 * 4 + r;
          bool ok = (MODE == 2) ? (key <= q) : (q - key < WINDOW);
          s[ni][r] = ok ? s[ni][r] : -1e30f;
        }
    }
    float pm0 = fmaxf(fmaxf(s[0][0], s[0][1]), fmaxf(s[0][2], s[0][3]));
    float pm1 = fmaxf(fmaxf(s[1][0], s[1][1]), fmaxf(s[1][2], s[1][3]));
    float pm2 = fmaxf(fmaxf(s[2][0], s[2][1]), fmaxf(s[2][2], s[2][3]));
    float pm3 = fmaxf(fmaxf(s[3][0], s[3][1]), fmaxf(s[3][2], s[3][3]));
    float pm = fmaxf(fmaxf(pm0, pm1), fmaxf(pm2, pm3));
    pm = fmaxf(pm, __shfl_xor(pm, 16, 64));
    pm = fmaxf(pm, __shfl_xor(pm, 32, 64));
    // defer-max: when no lane's max grew, alpha==1 exactly -> skip rescale pass
    if (!__all(pm <= m)) {
      float mn = fmaxf(m, pm);
      float alpha = __expf(m - mn);
      m = mn;
      lsum *= alpha;
#pragma unroll
      for (int ni = 0; ni < 4; ni++)
#pragma unroll
        for (int r = 0; r < 4; r++) o[ni][r] *= alpha;
    }
    float rs = 0.f;
#pragma unroll
    for (int ni = 0; ni < 4; ni++)
#pragma unroll
      for (int r = 0; r < 4; r++) {
        float p = __expf(s[ni][r] - m);
        s[ni][r] = p;
        rs += p;
      }
    rs += __shfl_xor(rs, 16, 64);
    rs += __shfl_xor(rs, 32, 64);
    lsum += rs;
    // P -> per-wave LDS (cvt_pk packed, row-XOR swizzled both sides)
#pragma unroll
    for (int ni = 0; ni < 4; ni++) {
      unsigned lo = cvtpk(s[ni][0], s[ni][1]);
      unsigned hi = cvtpk(s[ni][2], s[ni][3]);
      unsigned long long pv = (unsigned long long)lo | ((unsigned long long)hi << 32);
      *(unsigned long long*)(pw + l15 * 128 + ((ni * 32 + l4 * 8) ^ xw)) = pv;
    }
    short8 pa0 = *(const short8*)(pw + l15 * 128 + ((l4 * 16) ^ xw));
    short8 pa1 = *(const short8*)(pw + l15 * 128 + ((64 + l4 * 16) ^ xw));
    __builtin_amdgcn_s_setprio(1);
#pragma unroll
    for (int ni = 0; ni < 4; ni++) {
      int rb = (ni * 16 + l15) * 128;
      short8 v0 = *(const short8*)(vb + rb + ((l4 * 16) ^ xw));
      short8 v1 = *(const short8*)(vb + rb + ((64 + l4 * 16) ^ xw));
      o[ni] = mfma16(v0, pa0, o[ni]);
      o[ni] = mfma16(v1, pa1, o[ni]);
    }
    __builtin_amdgcn_s_setprio(0);
  };

  int kt0 = qb >= 4 ? qb - 4 : 0;
  int NT = qb - kt0 + 1;
  stage(kt0, 0);
  for (int t = 0; t < NT; t++) {
    int kt = kt0 + t;
    if (t + 1 < NT) {
      stage(kt + 1, (t + 1) & 1);
      asm volatile("s_waitcnt vmcnt(4)" ::: "memory");
    } else {
      asm volatile("s_waitcnt vmcnt(0)" ::: "memory");
    }
    __builtin_amdgcn_s_barrier();
    __builtin_amdgcn_sched_barrier(0);
    int MODE = (t == NT - 1) ? 2 : ((qb >= 4 && t == 0) ? 1 : 0);
    compute(kt, t & 1, MODE);
    __builtin_amdgcn_sched_barrier(0);
    __builtin_amdgcn_s_barrier();
  }

  float inv = 1.f / lsum;
#pragma unroll
  for (int ni = 0; ni < 4; ni++) {
    unsigned lo = cvtpk(o[ni][0] * inv, o[ni][1] * inv);
    unsigned hi = cvtpk(o[ni][2] * inv, o[ni][3] * inv);
    unsigned long long yv = (unsigned long long)lo | ((unsigned long long)hi << 32);
    *(unsigned long long*)(Y + (size_t)q * DMODEL + h * 64 + ni * 16 + l4 * 4) = yv;
  }
}

// ---------------- launch ----------------

extern "C" void kernel_launch(void* const* d_in, const int* in_sizes, int n_in,
                              void* d_out, int out_size, void* d_ws, size_t ws_size,
                              hipStream_t stream) {
  const float* x = (const float*)d_in[0];
  const float* Wqkv = (const float*)d_in[1];
  const float* bqkv = (const float*)d_in[2];
  const float* Wproj = (const float*)d_in[3];
  const float* bproj = (const float*)d_in[4];
  float* out = (float*)d_out;

  unsigned short* ws = (unsigned short*)d_ws;
  unsigned short* wqkvT = ws;                                     // [3072][1024]
  unsigned short* wprojT = wqkvT + (size_t)N3 * DMODEL;           // [1024][1024]
  unsigned short* qarr = wprojT + (size_t)DMODEL * DMODEL;        // [16][4096][64] (pre-scaled 1/8)
  unsigned short* karr = qarr + (size_t)NHEADS * TSEQ * HDIM;     // [16][4096][64]
  unsigned short* vtarr = karr + (size_t)NHEADS * TSEQ * HDIM;    // [16][64][4096]
  unsigned short* yarr = vtarr + (size_t)NHEADS * TSEQ * HDIM;    // [4096][1024]

  prep<<<dim3(128, 32), 256, 0, stream>>>(Wqkv, Wproj, wqkvT, wprojT);
  gemm_bf16<0, true, 4, 4><<<dim3(TSEQ / 128, N3 / 128), 256, 0, stream>>>(
      x, wqkvT, bqkv, qarr, karr, vtarr, nullptr);
  attn_swa<<<1024, 256, 0, stream>>>(qarr, karr, vtarr, yarr);
  gemm_bf16<1, false, 2, 2><<<dim3(TSEQ / 64, DMODEL / 64), 256, 0, stream>>>(
      yarr, wprojT, bproj, nullptr, nullptr, nullptr, out);
}

// Round 10
// 83.788 us; speedup vs baseline: 1.1100x; 1.0482x over previous
//
#include <hip/hip_runtime.h>
#include <stdint.h>

#define TSEQ 4096
#define DMODEL 1024
#define N3 3072
#define NHEADS 16
#define HDIM 64
#define WINDOW 256

typedef __attribute__((ext_vector_type(8))) short short8;
typedef __attribute__((ext_vector_type(4))) float f32x4;

__device__ __forceinline__ unsigned short f2bf(float f) {
  unsigned u = __builtin_bit_cast(unsigned, f);
  return (unsigned short)((u + 0x7fffu + ((u >> 16) & 1u)) >> 16);
}

__device__ __forceinline__ unsigned cvtpk(float lo, float hi) {
  unsigned r;
  asm("v_cvt_pk_bf16_f32 %0, %1, %2" : "=v"(r) : "v"(lo), "v"(hi));
  return r;
}

__device__ __forceinline__ f32x4 mfma16(short8 a, short8 b, f32x4 c) {
  return __builtin_amdgcn_mfma_f32_16x16x32_bf16(a, b, c, 0, 0, 0);
}

// async global->LDS, 16B per lane; lds dest must be wave-uniform base (HW adds lane*16)
__device__ __forceinline__ void g2lds16(const void* g, void* l) {
  __builtin_amdgcn_global_load_lds(
      (const __attribute__((address_space(1))) void*)(uintptr_t)g,
      (__attribute__((address_space(3))) void*)(uintptr_t)l,
      16, 0, 0);
}

// ---------------- fused prep: x cvt + both weight transposes ----------------
// blocks [0,4096): x f32 -> bf16 (16B/thread). blocks [4096,8192): 32x32 transpose tiles.

__global__ __launch_bounds__(256) void prep(const float* __restrict__ x,
                                            const float* __restrict__ Wqkv,
                                            const float* __restrict__ Wproj,
                                            unsigned short* __restrict__ xb,
                                            unsigned short* __restrict__ oQkvT,
                                            unsigned short* __restrict__ oProjT) {
  __shared__ float tile[32][33];
  int b = blockIdx.x;
  int tid = threadIdx.x;
  if (b < 4096) {
    int i = (b * 256 + tid) * 4;
    float4 v = *(const float4*)(x + i);
    unsigned lo = cvtpk(v.x, v.y), hi = cvtpk(v.z, v.w);
    unsigned long long packed = (unsigned long long)lo | ((unsigned long long)hi << 32);
    *(unsigned long long*)(xb + i) = packed;
    return;
  }
  b -= 4096;
  int bx = b & 127, by = b >> 7;
  const float* in;
  unsigned short* out;
  int C;
  if (bx < 96) {
    in = Wqkv; out = oQkvT; C = N3;
  } else {
    bx -= 96; in = Wproj; out = oProjT; C = DMODEL;
  }
  const int R = DMODEL;
  int c0 = bx * 32;
  int r0 = by * 32;
  int tx = tid & 31, ty = tid >> 5;
#pragma unroll
  for (int i = 0; i < 32; i += 8)
    tile[ty + i][tx] = in[(size_t)(r0 + ty + i) * C + c0 + tx];
  __syncthreads();
#pragma unroll
  for (int i = 0; i < 32; i += 8)
    out[(size_t)(c0 + ty + i) * R + r0 + tx] = f2bf(tile[tx][ty + i]);
}

// ---------------- GEMM: C[M][N] = A[M][K=1024] * BT[N][K]^T + bias ----------------
// Tile (MI*32)x(NI*32). EPI=0: scatter Q (pre-scaled 1/8), K, VT. EPI=1: f32 out.
// r5-proven structure (best of 6 schedule variants r4-r9): 2-buffer ping-pong,
// counted vmcnt (stage s+1 in flight across compute s), 2 barriers/step, bf16 A.
// Staging source pre-swizzled by ((row>>1)&3)<<4, same XOR on LDS read (rule 21):
// bank conflicts measured 0 (r5). AF32 experiment (r9) regressed: reverted.

template <int EPI, int MI, int NI>
__global__ __launch_bounds__(256)
void gemm_bf16(const unsigned short* __restrict__ A,
               const unsigned short* __restrict__ BT,
               const float* __restrict__ bias,
               unsigned short* __restrict__ oQ,
               unsigned short* __restrict__ oK,
               unsigned short* __restrict__ oVT,
               float* __restrict__ oF) {
  constexpr int BM = MI * 32, BN = NI * 32;
  constexpr int LPS = MI / 2 + NI / 2;  // g2lds per wave per stage
  __shared__ unsigned short Asm[2][BM * 32];
  __shared__ unsigned short Bsm[2][BN * 32];
  const int K = 1024;
  int m0 = blockIdx.x * BM;   // no XCD swizzle: default bx%8 partitioning already
  int n0 = blockIdx.y * BN;   // splits A-panels across XCDs (round-2 post-mortem)
  int tid = threadIdx.x;
  int w = tid >> 6, lane = tid & 63;
  int l15 = lane & 15, l4 = lane >> 4;
  int wm = (w >> 1) * (MI * 16), wn = (w & 1) * (NI * 16);

  f32x4 acc[MI][NI];
#pragma unroll
  for (int i = 0; i < MI; i++)
#pragma unroll
    for (int j = 0; j < NI; j++) acc[i][j] = (f32x4){0.f, 0.f, 0.f, 0.f};

  int lr = lane >> 2;
  int slot = ((lane & 3) * 16) ^ (((lr >> 1) & 3) << 4);
  const char* aG = (const char*)(A + (size_t)(m0 + w * (MI * 8) + lr) * K) + slot;
  const char* bG = (const char*)(BT + (size_t)(n0 + w * (NI * 8) + lr) * K) + slot;

  auto stage = [&](int s, int b) {   // step s covers k = s*32..s*32+31
    int koff = s * 64;               // bytes within row
#pragma unroll
    for (int c = 0; c < MI / 2; c++)
      g2lds16(aG + (size_t)c * 16 * 2048 + koff, &Asm[b][(w * (MI / 2) + c) * 512]);
#pragma unroll
    for (int j = 0; j < NI / 2; j++)
      g2lds16(bG + (size_t)j * 16 * 2048 + koff, &Bsm[b][(w * (NI / 2) + j) * 512]);
  };

  int sX = ((l15 >> 1) & 3) << 4;    // read-side swizzle (row bits 1-2 == l15 bits 1-2)

  auto compute = [&](int b) {
    short8 af[MI], bfr[NI];
#pragma unroll
    for (int mi = 0; mi < MI; mi++) {
      int rA = wm + mi * 16 + l15;
      af[mi] = *(const short8*)((const char*)Asm[b] + rA * 64 + ((l4 * 16) ^ sX));
    }
#pragma unroll
    for (int ni = 0; ni < NI; ni++) {
      int rB = wn + ni * 16 + l15;
      bfr[ni] = *(const short8*)((const char*)Bsm[b] + rB * 64 + ((l4 * 16) ^ sX));
    }
#pragma unroll
    for (int mi = 0; mi < MI; mi++)
#pragma unroll
      for (int ni = 0; ni < NI; ni++)
        acc[mi][ni] = mfma16(af[mi], bfr[ni], acc[mi][ni]);
  };

  const int NS = K / 32;  // 32 steps
  stage(0, 0);
#pragma unroll 1
  for (int s = 0; s < NS; s++) {
    if (s + 1 < NS) {
      stage(s + 1, (s + 1) & 1);
      // stage(s) landed; stage(s+1)'s LPS loads stay in flight
      if constexpr (LPS == 4) asm volatile("s_waitcnt vmcnt(4)" ::: "memory");
      else asm volatile("s_waitcnt vmcnt(2)" ::: "memory");
    } else {
      asm volatile("s_waitcnt vmcnt(0)" ::: "memory");
    }
    __builtin_amdgcn_s_barrier();
    __builtin_amdgcn_sched_barrier(0);
    compute(s & 1);
    __builtin_amdgcn_sched_barrier(0);
    __builtin_amdgcn_s_barrier();   // all waves done reading buf before it's restaged
  }

#pragma unroll
  for (int ni = 0; ni < NI; ni++) {
    int nn = n0 + wn + ni * 16 + l15;
    float bv = bias[nn];
    int c = nn & 1023;
    int hh = c >> 6, dd = c & 63;
#pragma unroll
    for (int mi = 0; mi < MI; mi++) {
      int mm = m0 + wm + mi * 16 + l4 * 4;
      float v0 = acc[mi][ni][0] + bv;
      float v1 = acc[mi][ni][1] + bv;
      float v2 = acc[mi][ni][2] + bv;
      float v3 = acc[mi][ni][3] + bv;
      if (EPI == 1) {
        oF[(size_t)(mm + 0) * 1024 + nn] = v0;
        oF[(size_t)(mm + 1) * 1024 + nn] = v1;
        oF[(size_t)(mm + 2) * 1024 + nn] = v2;
        oF[(size_t)(mm + 3) * 1024 + nn] = v3;
      } else if (nn < 1024) {
        oQ[((size_t)hh * TSEQ + mm + 0) * 64 + dd] = f2bf(v0 * 0.125f);
        oQ[((size_t)hh * TSEQ + mm + 1) * 64 + dd] = f2bf(v1 * 0.125f);
        oQ[((size_t)hh * TSEQ + mm + 2) * 64 + dd] = f2bf(v2 * 0.125f);
        oQ[((size_t)hh * TSEQ + mm + 3) * 64 + dd] = f2bf(v3 * 0.125f);
      } else if (nn < 2048) {
        oK[((size_t)hh * TSEQ + mm + 0) * 64 + dd] = f2bf(v0);
        oK[((size_t)hh * TSEQ + mm + 1) * 64 + dd] = f2bf(v1);
        oK[((size_t)hh * TSEQ + mm + 2) * 64 + dd] = f2bf(v2);
        oK[((size_t)hh * TSEQ + mm + 3) * 64 + dd] = f2bf(v3);
      } else {
        unsigned lo = cvtpk(v0, v1), hi = cvtpk(v2, v3);
        unsigned long long pv = (unsigned long long)lo | ((unsigned long long)hi << 32);
        *(unsigned long long*)(oVT + ((size_t)hh * 64 + dd) * TSEQ + mm) = pv;
      }
    }
  }
}

// ---------------- sliding-window attention (paired-qb, 8-wave, shared staging) ----------------
// grid 512 (XCD-swizzled), 512 threads. Block = (h, qb2): waves 0-3 own qb=2*qb2,
// waves 4-7 own qb+1 (16 q-rows each, same per-wave code as before). The two groups
// SHARE the staged K/V window: 6 tiles staged once instead of 5+5 across two blocks
// (-40% staging traffic); occupancy stays 2 blocks x 8 waves = 16 waves/CU.
// Per tile: 8 waves stage K(8KB)+V(8KB) (1 g2lds each), double-buffered, vmcnt(2).
// Edge tiles: inactive group skips compute (wave-uniform; barriers outside branch).
// S^T = mfma(K,Q); PV = mfma(V,P^T): softmax + rescale + 1/l all lane-local.
// setprio around MFMA (T5, m191); defer-max (T13, exact: alpha==1 when __all(pm<=m)).

__global__ __launch_bounds__(512)
void attn_swa(const unsigned short* __restrict__ Qa,
              const unsigned short* __restrict__ Ka,
              const unsigned short* __restrict__ Vt,
              unsigned short* __restrict__ Y) {
  __shared__ __align__(16) char KV[2][16384];   // [buf][ K 8KB | V 8KB ]
  __shared__ __align__(16) unsigned char Pl[8][2048];
  int flat = blockIdx.x;
  int swz = (flat & 7) * 64 + (flat >> 3);   // 512 blocks, bijective; 2 heads/XCD
  int h = swz >> 5, qb2 = swz & 31;
  int w = threadIdx.x >> 6, lane = threadIdx.x & 63;
  int l15 = lane & 15, l4 = lane >> 4;
  int g = w >> 2, wv = w & 3;
  int qb = qb2 * 2 + g;                      // this wave's q-block
  int qrow0 = qb * 64 + wv * 16;
  int q = qrow0 + l15;

  // Q fragments (pre-scaled by 1/8 in the QKV epilogue)
  const unsigned short* qp = Qa + ((size_t)h * TSEQ + q) * 64 + l4 * 8;
  short8 qf0 = *(const short8*)qp;
  short8 qf1 = *(const short8*)(qp + 32);

  const char* kgb = (const char*)(Ka + (size_t)h * TSEQ * 64);
  const char* vgb = (const char*)(Vt + (size_t)h * 64 * TSEQ);

  // stage tile kt into buffer b: wave w covers K rows w*8..+7 and V d-rows w*8..+7
  int sub8 = lane >> 3, slot = (lane & 7) * 16;
  int r8 = w * 8 + sub8;                     // r8&7 == sub8
  auto stage = [&](int kt, int b) {
    int kbase = kt * 64;
    g2lds16(kgb + (size_t)(kbase + r8) * 128 + (slot ^ (sub8 << 4)), &KV[b][w * 1024]);
    g2lds16(vgb + (size_t)r8 * 8192 + (size_t)kbase * 2 + (slot ^ (sub8 << 4)),
            &KV[b][8192 + w * 1024]);
  };

  float m = -1e30f, lsum = 0.f;
  f32x4 o[4];
#pragma unroll
  for (int ni = 0; ni < 4; ni++) o[ni] = (f32x4){0.f, 0.f, 0.f, 0.f};

  unsigned char* pw = Pl[w];
  int xw = (l15 & 7) << 4;  // row&7 == l15&7 for rows ni*16+l15

  // MODE: 0 = interior, 1 = window edge (q-key<256), 2 = causal diag (key<=q)
  auto compute = [&](int kt, int b, int MODE) {
    int kbase = kt * 64;
    const char* kb = KV[b];
    const char* vb = KV[b] + 8192;
    f32x4 s[4];
    __builtin_amdgcn_s_setprio(1);
#pragma unroll
    for (int ni = 0; ni < 4; ni++) {
      int rb = (ni * 16 + l15) * 128;
      short8 k0 = *(const short8*)(kb + rb + ((l4 * 16) ^ xw));
      short8 k1 = *(const short8*)(kb + rb + ((64 + l4 * 16) ^ xw));
      f32x4 z = (f32x4){0.f, 0.f, 0.f, 0.f};
      z = mfma16(k0, qf0, z);
      s[ni] = mfma16(k1, qf1, z);
    }
    __builtin_amdgcn_s_setprio(0);
    if (MODE != 0) {
#pragma unroll
      for (int ni = 0; ni < 4; ni++)
#pragma unroll
        for (int r = 0; r < 4; r++) {
          int key = kbase + ni * 16 + l4 * 4 + r;
          bool ok = (MODE == 2) ? (key <= q) : (q - key < WINDOW);
          s[ni][r] = ok ? s[ni][r] : -1e30f;
        }
    }
    float pm0 = fmaxf(fmaxf(s[0][0], s[0][1]), fmaxf(s[0][2], s[0][3]));
    float pm1 = fmaxf(fmaxf(s[1][0], s[1][1]), fmaxf(s[1][2], s[1][3]));
    float pm2 = fmaxf(fmaxf(s[2][0], s[2][1]), fmaxf(s[2][2], s[2][3]));
    float pm3 = fmaxf(fmaxf(s[3][0], s[3][1]), fmaxf(s[3][2], s[3][3]));
    float pm = fmaxf(fmaxf(pm0, pm1), fmaxf(pm2, pm3));
    pm = fmaxf(pm, __shfl_xor(pm, 16, 64));
    pm = fmaxf(pm, __shfl_xor(pm, 32, 64));
    // defer-max: when no lane's max grew, alpha==1 exactly -> skip rescale pass
    if (!__all(pm <= m)) {
      float mn = fmaxf(m, pm);
      float alpha = __expf(m - mn);
      m = mn;
      lsum *= alpha;
#pragma unroll
      for (int ni = 0; ni < 4; ni++)
#pragma unroll
        for (int r = 0; r < 4; r++) o[ni][r] *= alpha;
    }
    float rs = 0.f;
#pragma unroll
    for (int ni = 0; ni < 4; ni++)
#pragma unroll
      for (int r = 0; r < 4; r++) {
        float p = __expf(s[ni][r] - m);
        s[ni][r] = p;
        rs += p;
      }
    rs += __shfl_xor(rs, 16, 64);
    rs += __shfl_xor(rs, 32, 64);
    lsum += rs;
    // P -> per-wave LDS (cvt_pk packed, row-XOR swizzled both sides)
#pragma unroll
    for (int ni = 0; ni < 4; ni++) {
      unsigned lo = cvtpk(s[ni][0], s[ni][1]);
      unsigned hi = cvtpk(s[ni][2], s[ni][3]);
      unsigned long long pv = (unsigned long long)lo | ((unsigned long long)hi << 32);
      *(unsigned long long*)(pw + l15 * 128 + ((ni * 32 + l4 * 8) ^ xw)) = pv;
    }
    short8 pa0 = *(const short8*)(pw + l15 * 128 + ((l4 * 16) ^ xw));
    short8 pa1 = *(const short8*)(pw + l15 * 128 + ((64 + l4 * 16) ^ xw));
    __builtin_amdgcn_s_setprio(1);
#pragma unroll
    for (int ni = 0; ni < 4; ni++) {
      int rb = (ni * 16 + l15) * 128;
      short8 v0 = *(const short8*)(vb + rb + ((l4 * 16) ^ xw));
      short8 v1 = *(const short8*)(vb + rb + ((64 + l4 * 16) ^ xw));
      o[ni] = mfma16(v0, pa0, o[ni]);
      o[ni] = mfma16(v1, pa1, o[ni]);
    }
    __builtin_amdgcn_s_setprio(0);
  };

  int qbA = qb2 * 2, qbB = qbA + 1;
  int ktLo = qbA >= 4 ? qbA - 4 : 0;
  int NT = qbB - ktLo + 1;
  stage(ktLo, 0);
  for (int t = 0; t < NT; t++) {
    int kt = ktLo + t;
    if (t + 1 < NT) {
      stage(kt + 1, (t + 1) & 1);
      asm volatile("s_waitcnt vmcnt(2)" ::: "memory");
    } else {
      asm volatile("s_waitcnt vmcnt(0)" ::: "memory");
    }
    __builtin_amdgcn_s_barrier();
    __builtin_amdgcn_sched_barrier(0);
    bool active = (g == 0) ? (kt <= qbA) : (kt >= qbB - 4);
    if (active) {
      int MODE = (kt == qb) ? 2 : ((qb >= 4 && kt == qb - 4) ? 1 : 0);
      compute(kt, t & 1, MODE);
    }
    __builtin_amdgcn_sched_barrier(0);
    __builtin_amdgcn_s_barrier();   // all waves done reading buf before it's restaged
  }

  float inv = 1.f / lsum;
#pragma unroll
  for (int ni = 0; ni < 4; ni++) {
    unsigned lo = cvtpk(o[ni][0] * inv, o[ni][1] * inv);
    unsigned hi = cvtpk(o[ni][2] * inv, o[ni][3] * inv);
    unsigned long long yv = (unsigned long long)lo | ((unsigned long long)hi << 32);
    *(unsigned long long*)(Y + (size_t)q * DMODEL + h * 64 + ni * 16 + l4 * 4) = yv;
  }
}

// ---------------- launch ----------------

extern "C" void kernel_launch(void* const* d_in, const int* in_sizes, int n_in,
                              void* d_out, int out_size, void* d_ws, size_t ws_size,
                              hipStream_t stream) {
  const float* x = (const float*)d_in[0];
  const float* Wqkv = (const float*)d_in[1];
  const float* bqkv = (const float*)d_in[2];
  const float* Wproj = (const float*)d_in[3];
  const float* bproj = (const float*)d_in[4];
  float* out = (float*)d_out;

  unsigned short* ws = (unsigned short*)d_ws;
  unsigned short* xb = ws;                                        // [4096][1024]
  unsigned short* wqkvT = xb + (size_t)TSEQ * DMODEL;             // [3072][1024]
  unsigned short* wprojT = wqkvT + (size_t)N3 * DMODEL;           // [1024][1024]
  unsigned short* qarr = wprojT + (size_t)DMODEL * DMODEL;        // [16][4096][64] (pre-scaled 1/8)
  unsigned short* karr = qarr + (size_t)NHEADS * TSEQ * HDIM;     // [16][4096][64]
  unsigned short* vtarr = karr + (size_t)NHEADS * TSEQ * HDIM;    // [16][64][4096]
  unsigned short* yarr = vtarr + (size_t)NHEADS * TSEQ * HDIM;    // [4096][1024]

  prep<<<8192, 256, 0, stream>>>(x, Wqkv, Wproj, xb, wqkvT, wprojT);
  gemm_bf16<0, 4, 4><<<dim3(TSEQ / 128, N3 / 128), 256, 0, stream>>>(
      xb, wqkvT, bqkv, qarr, karr, vtarr, nullptr);
  attn_swa<<<512, 512, 0, stream>>>(qarr, karr, vtarr, yarr);
  gemm_bf16<1, 2, 2><<<dim3(TSEQ / 64, DMODEL / 64), 256, 0, stream>>>(
      yarr, wprojT, bproj, nullptr, nullptr, nullptr, out);
}